// Round 3
// baseline (432.023 us; speedup 1.0000x reference)
//
#include <hip/hip_runtime.h>
#include <math.h>

// Problem constants (match reference)
#define BB 4
#define NN 2048
#define CC 64
#define HH 512
#define WW 512
#define GS 8
#define HG 64
#define WG 64
#define MM 4096          // HG*WG
#define EPSF 1e-8f
#define NUM_NEG 4
#define MARGINF 1.0f

typedef __attribute__((ext_vector_type(8))) short short8;   // 8 bf16 (4 VGPRs)
typedef __attribute__((ext_vector_type(4))) float f32x4;

__device__ __forceinline__ unsigned short f32_to_bf16_rne(float x) {
    unsigned int u = __float_as_uint(x);
    u += 0x7fffu + ((u >> 16) & 1u);
    return (unsigned short)(u >> 16);
}

// ---------------------------------------------------------------------------
// Kernel 1: average-pool desc2 (B x C x H x W) over 8x8 blocks -> cells (B x M x C)
// One wave per (b, c, gy); lane = gx. Fully coalesced 1KB-per-instr float4 reads.
// HBM floor: 256 MB read ~= 42 us.
// ---------------------------------------------------------------------------
__global__ __launch_bounds__(256) void pool_kernel(const float* __restrict__ desc2,
                                                   float* __restrict__ cells) {
    int wave = blockIdx.x * 4 + (threadIdx.x >> 6);   // 0 .. B*C*HG-1
    int lane = threadIdx.x & 63;
    int gy = wave & 63;
    int c  = (wave >> 6) & 63;
    int b  = wave >> 12;
    const float* base = desc2 + (((size_t)b * CC + c) * HH + (size_t)gy * GS) * WW;
    // lane owns cell gx = lane; but read coalesced: float4 at [lane] and [lane+64],
    // then sum-of-8 within the lane's own 8-float window via cross-pattern:
    // row of 512 floats = 128 float4; lane reads f4[lane] (x 0..255) and f4[lane+64].
    // f4[j] covers x = 4j..4j+3 -> cell gx = j>>1. That is NOT lane's cell, so
    // instead accumulate per-pair and shuffle-combine: f4[2*gx], f4[2*gx+1].
    // Keep it simple and still coalesced: two instrs at 32B lane-stride cover the
    // row; each lane sums its own cell's 8 floats.
    float s = 0.f;
#pragma unroll
    for (int yy = 0; yy < GS; ++yy) {
        const float4* rp = (const float4*)(base + (size_t)yy * WW) + lane * 2;
        float4 a = rp[0];
        float4 d = rp[1];
        s += a.x + a.y + a.z + a.w + d.x + d.y + d.z + d.w;
    }
    s *= (1.0f / 64.0f);
    cells[((size_t)b * MM + (size_t)gy * WG + lane) * CC + c] = s;
}

// ---------------------------------------------------------------------------
// Kernel 2: L2-normalize each cell -> bf16 copy for MFMA + cn = ||cell_n||^2.
// One wave per cell; lane = channel.
// ---------------------------------------------------------------------------
__global__ __launch_bounds__(256) void normcells_kernel(const float* __restrict__ cells,
                                                        unsigned short* __restrict__ cells_bf,
                                                        float* __restrict__ cn) {
    int wave = blockIdx.x * 4 + (threadIdx.x >> 6);   // 0 .. B*M-1
    int lane = threadIdx.x & 63;
    size_t idx = (size_t)wave * CC + lane;
    float v = cells[idx];
    float ss = v * v;
#pragma unroll
    for (int off = 32; off; off >>= 1) ss += __shfl_xor(ss, off, 64);
    float norm = sqrtf(ss);
    float inv = 1.0f / (norm + EPSF);
    cells_bf[idx] = f32_to_bf16_rne(v * inv);
    if (lane == 0) {
        float r = norm * inv;
        cn[wave] = r * r;
    }
}

// ---------------------------------------------------------------------------
// Kernel 3: bilinear-sample positives, d_pos, an, bf16 copy of kp1_desc.
// One wave per keypoint; lane = channel.
// ---------------------------------------------------------------------------
__global__ __launch_bounds__(256) void pos_kernel(const float* __restrict__ w_kp1,
                                                  const float* __restrict__ kp1_desc,
                                                  const float* __restrict__ desc2,
                                                  float* __restrict__ dpos,
                                                  float* __restrict__ an,
                                                  unsigned short* __restrict__ kp_bf) {
    int kp = blockIdx.x * 4 + (threadIdx.x >> 6);     // b*N + n
    int lane = threadIdx.x & 63;
    int b = kp >> 11;                                 // / N
    float wx = w_kp1[(size_t)kp * 2 + 0];
    float wy = w_kp1[(size_t)kp * 2 + 1];
    float x = fminf(fmaxf(wx, 0.f), (float)(WW - 1));
    float y = fminf(fmaxf(wy, 0.f), (float)(HH - 1));
    float x0 = floorf(x), y0 = floorf(y);
    int x0i = (int)x0, y0i = (int)y0;
    int x1i = min(x0i + 1, WW - 1);
    int y1i = min(y0i + 1, HH - 1);
    float fx = x - x0, fy = y - y0;
    const float* p = desc2 + ((size_t)b * CC + lane) * (size_t)HH * WW;
    float v00 = p[(size_t)y0i * WW + x0i];
    float v01 = p[(size_t)y0i * WW + x1i];
    float v10 = p[(size_t)y1i * WW + x0i];
    float v11 = p[(size_t)y1i * WW + x1i];
    float pos = (1.f - fy) * (1.f - fx) * v00 + (1.f - fy) * fx * v01
              + fy * (1.f - fx) * v10 + fy * fx * v11;
    float ss = pos * pos;
#pragma unroll
    for (int off = 32; off; off >>= 1) ss += __shfl_xor(ss, off, 64);
    float posn = pos / (sqrtf(ss) + EPSF);
    float kd = kp1_desc[(size_t)kp * CC + lane];
    kp_bf[(size_t)kp * CC + lane] = f32_to_bf16_rne(kd);
    float diff = kd - posn;
    float dd = diff * diff;
    float aa = kd * kd;
#pragma unroll
    for (int off = 32; off; off >>= 1) {
        dd += __shfl_xor(dd, off, 64);
        aa += __shfl_xor(aa, off, 64);
    }
    if (lane == 0) {
        dpos[kp] = sqrtf(dd + EPSF);
        an[kp] = aa;
    }
}

// ---------------------------------------------------------------------------
// Kernel 4: MFMA distance matrix + mask + per-partition top-4 (in d^2 space).
// 16 partitions of 256 cells -> 2048 blocks (~8 blocks/CU for latency hiding).
// Block = 4 waves = 64 kps; each wave: 16 kps x 256-cell partition (16 tiles).
// Explicit register double-buffer of next tile's B-fragments + cn so vmcnt
// waits land one iteration ahead of use.
// D layout: col = lane&15 (cell), row = (lane>>4)*4 + reg (kp)  [m89/m91].
// ---------------------------------------------------------------------------
#define NPART 16
#define INS4(T0,T1,T2,T3,V) do { \
    T3 = fminf(T3, fmaxf(T2, V)); \
    T2 = fminf(T2, fmaxf(T1, V)); \
    T1 = fminf(T1, fmaxf(T0, V)); \
    T0 = fminf(T0, V); } while (0)

__global__ __launch_bounds__(256) void loss_mfma_kernel(const unsigned short* __restrict__ cells_bf,
                                                        const float* __restrict__ cn,
                                                        const unsigned short* __restrict__ kp_bf,
                                                        const float* __restrict__ w_kp1,
                                                        const float* __restrict__ an,
                                                        float* __restrict__ cand) {
    __shared__ float mg[4][16][16][4];   // [wave][kp_local][cell-lane][4] = 16 KB

    int b   = blockIdx.y;
    int kpg = blockIdx.x >> 4;           // 0..31  (group of 64 kps)
    int p   = blockIdx.x & (NPART - 1);  // cell partition (256 cells each)
    int tid = threadIdx.x;
    int w   = tid >> 6;                  // wave 0..3
    int L   = tid & 63;
    int q   = L >> 4;                    // quad
    int r   = L & 15;

    int n0 = kpg * 64 + w * 16;          // kp-tile base (within batch)

    // A fragments (kp descriptors), loaded once: row n0+r, k = q*8.. and +32
    const short8* arow = (const short8*)(kp_bf + (size_t)(b * NN + n0 + r) * CC);
    short8 afrag0 = arow[q];
    short8 afrag1 = arow[q + 4];

    // per-reg kp scalars: kp = n0 + q*4 + j
    const float4* anp = (const float4*)(an + (size_t)b * NN + n0 + q * 4);
    float4 an4 = anp[0];
    const float4* wp = (const float4*)(w_kp1 + (size_t)(b * NN + n0 + q * 4) * 2);
    float4 wA = wp[0], wB = wp[1];
    float wx0 = wA.x, wy0 = wA.y, wx1 = wA.z, wy1 = wA.w;
    float wx2 = wB.x, wy2 = wB.y, wx3 = wB.z, wy3 = wB.w;

    float t00 = 1e30f, t01 = 1e30f, t02 = 1e30f, t03 = 1e30f;
    float t10 = 1e30f, t11 = 1e30f, t12 = 1e30f, t13 = 1e30f;
    float t20 = 1e30f, t21 = 1e30f, t22 = 1e30f, t23 = 1e30f;
    float t30 = 1e30f, t31 = 1e30f, t32 = 1e30f, t33 = 1e30f;

    const unsigned short* cellb = cells_bf + (size_t)b * MM * CC;
    const float* cnb = cn + (size_t)b * MM;
    const int mbase = p * (MM / NPART);

    // prefetch tile 0
    short8 cb0, cb1; float ccn;
    {
        int m = mbase + r;
        const short8* br = (const short8*)(cellb + (size_t)m * CC);
        cb0 = br[q]; cb1 = br[q + 4];
        ccn = cnb[m];
    }

#pragma unroll
    for (int t = 0; t < MM / NPART / 16; ++t) {
        short8 nb0, nb1; float ncn;
        if (t < MM / NPART / 16 - 1) {
            int m = mbase + (t + 1) * 16 + r;
            const short8* br = (const short8*)(cellb + (size_t)m * CC);
            nb0 = br[q]; nb1 = br[q + 4];
            ncn = cnb[m];
        }

        f32x4 acc = {0.f, 0.f, 0.f, 0.f};
        acc = __builtin_amdgcn_mfma_f32_16x16x32_bf16(afrag0, cb0, acc, 0, 0, 0);
        acc = __builtin_amdgcn_mfma_f32_16x16x32_bf16(afrag1, cb1, acc, 0, 0, 0);

        int m = mbase + t * 16 + r;
        float cxl = (float)((m & 63) * 8 + 4);
        float cyl = (float)((m >> 6) * 8 + 4);

        {
            float d2 = fmaf(-2.f, acc[0], an4.x + ccn);
            float dx = wx0 - cxl, dy = wy0 - cyl;
            float v = (fmaf(dx, dx, dy * dy) <= 64.f) ? 1e12f : d2;
            INS4(t00, t01, t02, t03, v);
        }
        {
            float d2 = fmaf(-2.f, acc[1], an4.y + ccn);
            float dx = wx1 - cxl, dy = wy1 - cyl;
            float v = (fmaf(dx, dx, dy * dy) <= 64.f) ? 1e12f : d2;
            INS4(t10, t11, t12, t13, v);
        }
        {
            float d2 = fmaf(-2.f, acc[2], an4.z + ccn);
            float dx = wx2 - cxl, dy = wy2 - cyl;
            float v = (fmaf(dx, dx, dy * dy) <= 64.f) ? 1e12f : d2;
            INS4(t20, t21, t22, t23, v);
        }
        {
            float d2 = fmaf(-2.f, acc[3], an4.w + ccn);
            float dx = wx3 - cxl, dy = wy3 - cyl;
            float v = (fmaf(dx, dx, dy * dy) <= 64.f) ? 1e12f : d2;
            INS4(t30, t31, t32, t33, v);
        }

        cb0 = nb0; cb1 = nb1; ccn = ncn;
    }

    // stash per-lane top4 lists: kp_local = q*4+j, cell-class = r
    {
        float4 v;
        v.x = t00; v.y = t01; v.z = t02; v.w = t03;
        *(float4*)&mg[w][q * 4 + 0][r][0] = v;
        v.x = t10; v.y = t11; v.z = t12; v.w = t13;
        *(float4*)&mg[w][q * 4 + 1][r][0] = v;
        v.x = t20; v.y = t21; v.z = t22; v.w = t23;
        *(float4*)&mg[w][q * 4 + 2][r][0] = v;
        v.x = t30; v.y = t31; v.z = t32; v.w = t33;
        *(float4*)&mg[w][q * 4 + 3][r][0] = v;
    }
    __syncthreads();

    // merge 16 lists of 4 per (wave, kp_local): 4 threads x 4 lists + butterfly
    int w2  = tid >> 6;
    int kl  = (tid >> 2) & 15;
    int seg = tid & 3;
    float m0v = 1e30f, m1v = 1e30f, m2v = 1e30f, m3v = 1e30f;
#pragma unroll
    for (int i = 0; i < 4; ++i) {
        float4 v = *(const float4*)&mg[w2][kl][seg * 4 + i][0];
        INS4(m0v, m1v, m2v, m3v, v.x);
        INS4(m0v, m1v, m2v, m3v, v.y);
        INS4(m0v, m1v, m2v, m3v, v.z);
        INS4(m0v, m1v, m2v, m3v, v.w);
    }
#pragma unroll
    for (int step = 1; step <= 2; step <<= 1) {
        float p0 = __shfl_xor(m0v, step, 64);
        float p1 = __shfl_xor(m1v, step, 64);
        float p2 = __shfl_xor(m2v, step, 64);
        float p3 = __shfl_xor(m3v, step, 64);
        INS4(m0v, m1v, m2v, m3v, p0);
        INS4(m0v, m1v, m2v, m3v, p1);
        INS4(m0v, m1v, m2v, m3v, p2);
        INS4(m0v, m1v, m2v, m3v, p3);
    }
    if (seg == 0) {
        size_t kp = (size_t)b * NN + kpg * 64 + w2 * 16 + kl;
        float4 v; v.x = m0v; v.y = m1v; v.z = m2v; v.w = m3v;
        *(float4*)(cand + kp * (NPART * 4) + p * 4) = v;
    }
}

// ---------------------------------------------------------------------------
// Kernel 5: per-kp merge of NPART partitions, sqrt, loss, block partial sums.
// One thread per keypoint.
// ---------------------------------------------------------------------------
__global__ __launch_bounds__(256) void merge_kernel(const float* __restrict__ cand,
                                                    const float* __restrict__ dpos,
                                                    float* __restrict__ partials) {
    __shared__ float s4[4];
    int kp = blockIdx.x * 256 + threadIdx.x;
    float m0 = 1e30f, m1 = 1e30f, m2 = 1e30f, m3 = 1e30f;
    const float4* cp = (const float4*)(cand + (size_t)kp * (NPART * 4));
#pragma unroll
    for (int i = 0; i < NPART; ++i) {
        float4 v = cp[i];
        INS4(m0, m1, m2, m3, v.x);
        INS4(m0, m1, m2, m3, v.y);
        INS4(m0, m1, m2, m3, v.z);
        INS4(m0, m1, m2, m3, v.w);
    }
    float dp = dpos[kp];
    float d0 = sqrtf(fmaxf(m0, 0.f) + EPSF);
    float d1 = sqrtf(fmaxf(m1, 0.f) + EPSF);
    float d2 = sqrtf(fmaxf(m2, 0.f) + EPSF);
    float d3 = sqrtf(fmaxf(m3, 0.f) + EPSF);
    float l = fmaxf(dp - d0 + MARGINF, 0.f)
            + fmaxf(dp - d1 + MARGINF, 0.f)
            + fmaxf(dp - d2 + MARGINF, 0.f)
            + fmaxf(dp - d3 + MARGINF, 0.f);
#pragma unroll
    for (int off = 32; off; off >>= 1) l += __shfl_xor(l, off, 64);
    if ((threadIdx.x & 63) == 0) s4[threadIdx.x >> 6] = l;
    __syncthreads();
    if (threadIdx.x == 0)
        partials[blockIdx.x] = s4[0] + s4[1] + s4[2] + s4[3];
}

// ---------------------------------------------------------------------------
// Kernel 6: reduce 32 block partials -> mean -> d_out[0]
// ---------------------------------------------------------------------------
__global__ __launch_bounds__(64) void finalize_kernel(const float* __restrict__ partials,
                                                      float* __restrict__ out) {
    int tid = threadIdx.x;
    float v = (tid < 32) ? partials[tid] : 0.f;
#pragma unroll
    for (int off = 32; off; off >>= 1) v += __shfl_xor(v, off, 64);
    if (tid == 0) out[0] = v * (1.0f / (float)(BB * NN * NUM_NEG));
}

extern "C" void kernel_launch(void* const* d_in, const int* in_sizes, int n_in,
                              void* d_out, int out_size, void* d_ws, size_t ws_size,
                              hipStream_t stream) {
    // inputs: 0=kp1 (unused), 1=w_kp1, 2=kp1_desc, 3=desc2, 4=homo12 (unused)
    const float* w_kp1    = (const float*)d_in[1];
    const float* kp1_desc = (const float*)d_in[2];
    const float* desc2    = (const float*)d_in[3];
    float* out = (float*)d_out;

    float* ws = (float*)d_ws;
    float* cells    = ws;                               // B*M*C   = 1,048,576 f
    float* cn       = cells + (size_t)BB * MM * CC;     // B*M     = 16,384 f
    float* dpos     = cn + (size_t)BB * MM;             // B*N     = 8,192 f
    float* an       = dpos + (size_t)BB * NN;           // B*N     = 8,192 f
    float* partials = an + (size_t)BB * NN;             // 32 f
    float* cand     = partials + 64;                    // B*N*64  = 524,288 f
    unsigned short* cells_bf = (unsigned short*)(cand + (size_t)BB * NN * NPART * 4);
    unsigned short* kp_bf    = cells_bf + (size_t)BB * MM * CC;

    pool_kernel<<<dim3(4096), dim3(256), 0, stream>>>(desc2, cells);
    normcells_kernel<<<dim3(4096), dim3(256), 0, stream>>>(cells, cells_bf, cn);
    pos_kernel<<<dim3(2048), dim3(256), 0, stream>>>(w_kp1, kp1_desc, desc2, dpos, an, kp_bf);
    loss_mfma_kernel<<<dim3(32 * NPART, BB), dim3(256), 0, stream>>>(
        cells_bf, cn, kp_bf, w_kp1, an, cand);
    merge_kernel<<<dim3(BB * NN / 256), dim3(256), 0, stream>>>(cand, dpos, partials);
    finalize_kernel<<<dim3(1), dim3(64), 0, stream>>>(partials, out);
}

// Round 4
// 430.146 us; speedup vs baseline: 1.0044x; 1.0044x over previous
//
#include <hip/hip_runtime.h>
#include <math.h>

// Problem constants (match reference)
#define BB 4
#define NN 2048
#define CC 64
#define HH 512
#define WW 512
#define GS 8
#define HG 64
#define WG 64
#define MM 4096          // HG*WG
#define EPSF 1e-8f
#define NUM_NEG 4
#define MARGINF 1.0f

typedef __attribute__((ext_vector_type(8))) short short8;   // 8 bf16 (4 VGPRs)
typedef __attribute__((ext_vector_type(4))) float f32x4;

__device__ __forceinline__ unsigned short f32_to_bf16_rne(float x) {
    unsigned int u = __float_as_uint(x);
    u += 0x7fffu + ((u >> 16) & 1u);
    return (unsigned short)(u >> 16);
}

// ---------------------------------------------------------------------------
// Kernel 1 (fused): blocks [0, 4096): average-pool desc2 -> cells (fp32).
//                   blocks [4096, 6144): bilinear-sample positives (independent
//                   of pool output; overlaps latency-bound gathers with the
//                   BW-bound streaming and reuses desc2 lines in L2/L3).
// ---------------------------------------------------------------------------
__global__ __launch_bounds__(256) void pool_pos_kernel(const float* __restrict__ desc2,
                                                       float* __restrict__ cells,
                                                       const float* __restrict__ w_kp1,
                                                       const float* __restrict__ kp1_desc,
                                                       float* __restrict__ dpos,
                                                       float* __restrict__ an,
                                                       unsigned short* __restrict__ kp_bf) {
    int lane = threadIdx.x & 63;
    if (blockIdx.x < 4096) {
        // ---- pool: one wave per (b, c, gy); lane = gx; coalesced 2KB/row ----
        int wave = blockIdx.x * 4 + (threadIdx.x >> 6);   // 0 .. B*C*HG-1
        int gy = wave & 63;
        int c  = (wave >> 6) & 63;
        int b  = wave >> 12;
        const float* base = desc2 + (((size_t)b * CC + c) * HH + (size_t)gy * GS) * WW;
        float s = 0.f;
#pragma unroll
        for (int yy = 0; yy < GS; ++yy) {
            const float4* rp = (const float4*)(base + (size_t)yy * WW) + lane * 2;
            float4 a = rp[0];
            float4 d = rp[1];
            s += a.x + a.y + a.z + a.w + d.x + d.y + d.z + d.w;
        }
        s *= (1.0f / 64.0f);
        cells[((size_t)b * MM + (size_t)gy * WG + lane) * CC + c] = s;
    } else {
        // ---- pos: one wave per keypoint; lane = channel ----
        int kp = (blockIdx.x - 4096) * 4 + (threadIdx.x >> 6);  // b*N + n
        int b = kp >> 11;
        float wx = w_kp1[(size_t)kp * 2 + 0];
        float wy = w_kp1[(size_t)kp * 2 + 1];
        float x = fminf(fmaxf(wx, 0.f), (float)(WW - 1));
        float y = fminf(fmaxf(wy, 0.f), (float)(HH - 1));
        float x0 = floorf(x), y0 = floorf(y);
        int x0i = (int)x0, y0i = (int)y0;
        int x1i = min(x0i + 1, WW - 1);
        int y1i = min(y0i + 1, HH - 1);
        float fx = x - x0, fy = y - y0;
        const float* p = desc2 + ((size_t)b * CC + lane) * (size_t)HH * WW;
        float v00 = p[(size_t)y0i * WW + x0i];
        float v01 = p[(size_t)y0i * WW + x1i];
        float v10 = p[(size_t)y1i * WW + x0i];
        float v11 = p[(size_t)y1i * WW + x1i];
        float pos = (1.f - fy) * (1.f - fx) * v00 + (1.f - fy) * fx * v01
                  + fy * (1.f - fx) * v10 + fy * fx * v11;
        float ss = pos * pos;
#pragma unroll
        for (int off = 32; off; off >>= 1) ss += __shfl_xor(ss, off, 64);
        float posn = pos / (sqrtf(ss) + EPSF);
        float kd = kp1_desc[(size_t)kp * CC + lane];
        kp_bf[(size_t)kp * CC + lane] = f32_to_bf16_rne(kd);
        float diff = kd - posn;
        float dd = diff * diff;
        float aa = kd * kd;
#pragma unroll
        for (int off = 32; off; off >>= 1) {
            dd += __shfl_xor(dd, off, 64);
            aa += __shfl_xor(aa, off, 64);
        }
        if (lane == 0) {
            dpos[kp] = sqrtf(dd + EPSF);
            an[kp] = aa;
        }
    }
}

// ---------------------------------------------------------------------------
// Kernel 2: L2-normalize each cell -> bf16 copy for MFMA + cn = ||cell_n||^2.
// One wave per cell; lane = channel.
// ---------------------------------------------------------------------------
__global__ __launch_bounds__(256) void normcells_kernel(const float* __restrict__ cells,
                                                        unsigned short* __restrict__ cells_bf,
                                                        float* __restrict__ cn) {
    int wave = blockIdx.x * 4 + (threadIdx.x >> 6);   // 0 .. B*M-1
    int lane = threadIdx.x & 63;
    size_t idx = (size_t)wave * CC + lane;
    float v = cells[idx];
    float ss = v * v;
#pragma unroll
    for (int off = 32; off; off >>= 1) ss += __shfl_xor(ss, off, 64);
    float norm = sqrtf(ss);
    float inv = 1.0f / (norm + EPSF);
    cells_bf[idx] = f32_to_bf16_rne(v * inv);
    if (lane == 0) {
        float r = norm * inv;
        cn[wave] = r * r;
    }
}

// ---------------------------------------------------------------------------
// Kernel 3: MFMA distance matrix + mask + per-partition top-4 (in d^2 space).
// 16 partitions of 256 cells -> 2048 blocks. Register double-buffered B-tiles.
// D layout: col = lane&15 (cell), row = (lane>>4)*4 + reg (kp)  [m89/m91].
// ---------------------------------------------------------------------------
#define NPART 16
#define INS4(T0,T1,T2,T3,V) do { \
    T3 = fminf(T3, fmaxf(T2, V)); \
    T2 = fminf(T2, fmaxf(T1, V)); \
    T1 = fminf(T1, fmaxf(T0, V)); \
    T0 = fminf(T0, V); } while (0)

__global__ __launch_bounds__(256) void loss_mfma_kernel(const unsigned short* __restrict__ cells_bf,
                                                        const float* __restrict__ cn,
                                                        const unsigned short* __restrict__ kp_bf,
                                                        const float* __restrict__ w_kp1,
                                                        const float* __restrict__ an,
                                                        float* __restrict__ cand) {
    __shared__ float mg[4][16][16][4];   // [wave][kp_local][cell-lane][4] = 16 KB

    int b   = blockIdx.y;
    int kpg = blockIdx.x >> 4;           // 0..31  (group of 64 kps)
    int p   = blockIdx.x & (NPART - 1);  // cell partition (256 cells each)
    int tid = threadIdx.x;
    int w   = tid >> 6;                  // wave 0..3
    int L   = tid & 63;
    int q   = L >> 4;                    // quad
    int r   = L & 15;

    int n0 = kpg * 64 + w * 16;          // kp-tile base (within batch)

    const short8* arow = (const short8*)(kp_bf + (size_t)(b * NN + n0 + r) * CC);
    short8 afrag0 = arow[q];
    short8 afrag1 = arow[q + 4];

    const float4* anp = (const float4*)(an + (size_t)b * NN + n0 + q * 4);
    float4 an4 = anp[0];
    const float4* wp = (const float4*)(w_kp1 + (size_t)(b * NN + n0 + q * 4) * 2);
    float4 wA = wp[0], wB = wp[1];
    float wx0 = wA.x, wy0 = wA.y, wx1 = wA.z, wy1 = wA.w;
    float wx2 = wB.x, wy2 = wB.y, wx3 = wB.z, wy3 = wB.w;

    float t00 = 1e30f, t01 = 1e30f, t02 = 1e30f, t03 = 1e30f;
    float t10 = 1e30f, t11 = 1e30f, t12 = 1e30f, t13 = 1e30f;
    float t20 = 1e30f, t21 = 1e30f, t22 = 1e30f, t23 = 1e30f;
    float t30 = 1e30f, t31 = 1e30f, t32 = 1e30f, t33 = 1e30f;

    const unsigned short* cellb = cells_bf + (size_t)b * MM * CC;
    const float* cnb = cn + (size_t)b * MM;
    const int mbase = p * (MM / NPART);

    short8 cb0, cb1; float ccn;
    {
        int m = mbase + r;
        const short8* br = (const short8*)(cellb + (size_t)m * CC);
        cb0 = br[q]; cb1 = br[q + 4];
        ccn = cnb[m];
    }

#pragma unroll
    for (int t = 0; t < MM / NPART / 16; ++t) {
        short8 nb0, nb1; float ncn;
        if (t < MM / NPART / 16 - 1) {
            int m = mbase + (t + 1) * 16 + r;
            const short8* br = (const short8*)(cellb + (size_t)m * CC);
            nb0 = br[q]; nb1 = br[q + 4];
            ncn = cnb[m];
        }

        f32x4 acc = {0.f, 0.f, 0.f, 0.f};
        acc = __builtin_amdgcn_mfma_f32_16x16x32_bf16(afrag0, cb0, acc, 0, 0, 0);
        acc = __builtin_amdgcn_mfma_f32_16x16x32_bf16(afrag1, cb1, acc, 0, 0, 0);

        int m = mbase + t * 16 + r;
        float cxl = (float)((m & 63) * 8 + 4);
        float cyl = (float)((m >> 6) * 8 + 4);

        {
            float d2 = fmaf(-2.f, acc[0], an4.x + ccn);
            float dx = wx0 - cxl, dy = wy0 - cyl;
            float v = (fmaf(dx, dx, dy * dy) <= 64.f) ? 1e12f : d2;
            INS4(t00, t01, t02, t03, v);
        }
        {
            float d2 = fmaf(-2.f, acc[1], an4.y + ccn);
            float dx = wx1 - cxl, dy = wy1 - cyl;
            float v = (fmaf(dx, dx, dy * dy) <= 64.f) ? 1e12f : d2;
            INS4(t10, t11, t12, t13, v);
        }
        {
            float d2 = fmaf(-2.f, acc[2], an4.z + ccn);
            float dx = wx2 - cxl, dy = wy2 - cyl;
            float v = (fmaf(dx, dx, dy * dy) <= 64.f) ? 1e12f : d2;
            INS4(t20, t21, t22, t23, v);
        }
        {
            float d2 = fmaf(-2.f, acc[3], an4.w + ccn);
            float dx = wx3 - cxl, dy = wy3 - cyl;
            float v = (fmaf(dx, dx, dy * dy) <= 64.f) ? 1e12f : d2;
            INS4(t30, t31, t32, t33, v);
        }

        cb0 = nb0; cb1 = nb1; ccn = ncn;
    }

    {
        float4 v;
        v.x = t00; v.y = t01; v.z = t02; v.w = t03;
        *(float4*)&mg[w][q * 4 + 0][r][0] = v;
        v.x = t10; v.y = t11; v.z = t12; v.w = t13;
        *(float4*)&mg[w][q * 4 + 1][r][0] = v;
        v.x = t20; v.y = t21; v.z = t22; v.w = t23;
        *(float4*)&mg[w][q * 4 + 2][r][0] = v;
        v.x = t30; v.y = t31; v.z = t32; v.w = t33;
        *(float4*)&mg[w][q * 4 + 3][r][0] = v;
    }
    __syncthreads();

    int w2  = tid >> 6;
    int kl  = (tid >> 2) & 15;
    int seg = tid & 3;
    float m0v = 1e30f, m1v = 1e30f, m2v = 1e30f, m3v = 1e30f;
#pragma unroll
    for (int i = 0; i < 4; ++i) {
        float4 v = *(const float4*)&mg[w2][kl][seg * 4 + i][0];
        INS4(m0v, m1v, m2v, m3v, v.x);
        INS4(m0v, m1v, m2v, m3v, v.y);
        INS4(m0v, m1v, m2v, m3v, v.z);
        INS4(m0v, m1v, m2v, m3v, v.w);
    }
#pragma unroll
    for (int step = 1; step <= 2; step <<= 1) {
        float p0 = __shfl_xor(m0v, step, 64);
        float p1 = __shfl_xor(m1v, step, 64);
        float p2 = __shfl_xor(m2v, step, 64);
        float p3 = __shfl_xor(m3v, step, 64);
        INS4(m0v, m1v, m2v, m3v, p0);
        INS4(m0v, m1v, m2v, m3v, p1);
        INS4(m0v, m1v, m2v, m3v, p2);
        INS4(m0v, m1v, m2v, m3v, p3);
    }
    if (seg == 0) {
        size_t kp = (size_t)b * NN + kpg * 64 + w2 * 16 + kl;
        float4 v; v.x = m0v; v.y = m1v; v.z = m2v; v.w = m3v;
        *(float4*)(cand + kp * (NPART * 4) + p * 4) = v;
    }
}

// ---------------------------------------------------------------------------
// Kernel 4: per-kp merge of NPART partitions, sqrt, loss, block partial sums.
// ---------------------------------------------------------------------------
__global__ __launch_bounds__(256) void merge_kernel(const float* __restrict__ cand,
                                                    const float* __restrict__ dpos,
                                                    float* __restrict__ partials) {
    __shared__ float s4[4];
    int kp = blockIdx.x * 256 + threadIdx.x;
    float m0 = 1e30f, m1 = 1e30f, m2 = 1e30f, m3 = 1e30f;
    const float4* cp = (const float4*)(cand + (size_t)kp * (NPART * 4));
#pragma unroll
    for (int i = 0; i < NPART; ++i) {
        float4 v = cp[i];
        INS4(m0, m1, m2, m3, v.x);
        INS4(m0, m1, m2, m3, v.y);
        INS4(m0, m1, m2, m3, v.z);
        INS4(m0, m1, m2, m3, v.w);
    }
    float dp = dpos[kp];
    float d0 = sqrtf(fmaxf(m0, 0.f) + EPSF);
    float d1 = sqrtf(fmaxf(m1, 0.f) + EPSF);
    float d2 = sqrtf(fmaxf(m2, 0.f) + EPSF);
    float d3 = sqrtf(fmaxf(m3, 0.f) + EPSF);
    float l = fmaxf(dp - d0 + MARGINF, 0.f)
            + fmaxf(dp - d1 + MARGINF, 0.f)
            + fmaxf(dp - d2 + MARGINF, 0.f)
            + fmaxf(dp - d3 + MARGINF, 0.f);
#pragma unroll
    for (int off = 32; off; off >>= 1) l += __shfl_xor(l, off, 64);
    if ((threadIdx.x & 63) == 0) s4[threadIdx.x >> 6] = l;
    __syncthreads();
    if (threadIdx.x == 0)
        partials[blockIdx.x] = s4[0] + s4[1] + s4[2] + s4[3];
}

// ---------------------------------------------------------------------------
// Kernel 5: reduce 32 block partials -> mean -> d_out[0]
// ---------------------------------------------------------------------------
__global__ __launch_bounds__(64) void finalize_kernel(const float* __restrict__ partials,
                                                      float* __restrict__ out) {
    int tid = threadIdx.x;
    float v = (tid < 32) ? partials[tid] : 0.f;
#pragma unroll
    for (int off = 32; off; off >>= 1) v += __shfl_xor(v, off, 64);
    if (tid == 0) out[0] = v * (1.0f / (float)(BB * NN * NUM_NEG));
}

extern "C" void kernel_launch(void* const* d_in, const int* in_sizes, int n_in,
                              void* d_out, int out_size, void* d_ws, size_t ws_size,
                              hipStream_t stream) {
    // inputs: 0=kp1 (unused), 1=w_kp1, 2=kp1_desc, 3=desc2, 4=homo12 (unused)
    const float* w_kp1    = (const float*)d_in[1];
    const float* kp1_desc = (const float*)d_in[2];
    const float* desc2    = (const float*)d_in[3];
    float* out = (float*)d_out;

    float* ws = (float*)d_ws;
    float* cells    = ws;                               // B*M*C   = 1,048,576 f
    float* cn       = cells + (size_t)BB * MM * CC;     // B*M     = 16,384 f
    float* dpos     = cn + (size_t)BB * MM;             // B*N     = 8,192 f
    float* an       = dpos + (size_t)BB * NN;           // B*N     = 8,192 f
    float* partials = an + (size_t)BB * NN;             // 32 f
    float* cand     = partials + 64;                    // B*N*64  = 524,288 f
    unsigned short* cells_bf = (unsigned short*)(cand + (size_t)BB * NN * NPART * 4);
    unsigned short* kp_bf    = cells_bf + (size_t)BB * MM * CC;

    // fused pool (blocks 0..4095) + pos (blocks 4096..6143)
    pool_pos_kernel<<<dim3(6144), dim3(256), 0, stream>>>(
        desc2, cells, w_kp1, kp1_desc, dpos, an, kp_bf);
    normcells_kernel<<<dim3(4096), dim3(256), 0, stream>>>(cells, cells_bf, cn);
    loss_mfma_kernel<<<dim3(32 * NPART, BB), dim3(256), 0, stream>>>(
        cells_bf, cn, kp_bf, w_kp1, an, cand);
    merge_kernel<<<dim3(BB * NN / 256), dim3(256), 0, stream>>>(cand, dpos, partials);
    finalize_kernel<<<dim3(1), dim3(64), 0, stream>>>(partials, out);
}